// Round 12
// baseline (143.719 us; speedup 1.0000x reference)
//
#include <hip/hip_runtime.h>

// KAN layer, R14. Two separable changes vs R13b (137.3; fused 48.6 stable):
//  (A) partials slice PADDED +9 KB (2304 floats): reduce16 read 16 streams at
//      exactly 4 MB stride = HBM channel/page alias suspect for the ~30 us
//      aux hole (fill 41 + fused 48.6 + aux 47.7 = 137.3; prep+reduce were
//      invisible below the 48.4 top-5 cutoff). Padding breaks the alias.
//      [decoded from: total - fused-row - fill]
//  (B) kan_fused GEN_AS: register-built record quads (compile-time-unrolled
//      selects vs runtime k0; static indexing) -> 4 clean ds_write_b128,
//      replacing 4xb128-zero + b32 + 5 scattered ds_write_u16 that caused the
//      measured 1.55M bank conflicts. Byte-identical record values.
//      [decoded from: fused top-5 row + SQ_LDS_BANK_CONFLICT]
// Carried: R11 fused structure (proven 48.6; R12's counted-vmcnt graft was
// -20 us, reverted), R12 prep_c32 (1 record/thread), KSPLIT=16, XCD pin.
// ws: Ct32 16.8 MB + padded partials 67.2 MB = 84 MB.

typedef _Float16 half_t;
typedef __attribute__((ext_vector_type(8))) _Float16 half8;
typedef __attribute__((ext_vector_type(4))) float floatx4;

#define B_DIM   2048
#define J_DIM   512
#define O_DIM   512
#define SLOT32  32
#define KT32    (J_DIM * SLOT32)     // 16384
#define BM      256
#define BN      256
#define KSPLIT  16                   // j-slice = 32 j = 16 phases of 2 j
#define NPH     16
#define SLICE_PAD 2304               // floats: 9 KB — breaks 4KB/channel align
#define SLICE_F (B_DIM * O_DIM + SLICE_PAD)

// ---------------------------------------------------------------------------
// Quartic B-spline local basis, uniform knots g_i = -1.5 + i*(3.125/24).
// (Reference quirk: linspace(-1.5, 1.625, 25) -> spacing 3.125/24, NOT 0.125.)
__device__ __forceinline__ void bspline5(float xc, int& k0, float Nv[5]) {
    const float invS = 7.68f;              // 24/3.125 (exact ratio)
    float u = (xc + 1.5f) * invS;          // knot units
    int m = (int)u;
    m = min(max(m, 3), 19);
    k0 = m - 4;
    Nv[0] = 1.f; Nv[1] = 0.f; Nv[2] = 0.f; Nv[3] = 0.f; Nv[4] = 0.f;
#pragma unroll
    for (int d = 1; d <= 4; ++d) {
        float nw[5];
        float inv_d = 1.0f / (float)d;
#pragma unroll
        for (int r = 0; r < 5; ++r) {
            if (r > d) { nw[r] = 0.f; continue; }
            float kk = (float)(m - d + r);
            float acc = 0.f;
            if (r >= 1) acc += (u - kk) * Nv[r - 1];
            if (r < d)  acc += (kk + (float)(d + 1) - u) * Nv[r];
            nw[r] = acc * inv_d;
        }
#pragma unroll
        for (int r = 0; r < 5; ++r) Nv[r] = nw[r];
    }
}

__device__ __forceinline__ unsigned packh2(float a, float b) {
    half_t ha = (half_t)a, hb = (half_t)b;    // RTN, identical to prior rounds
    unsigned short ua = __builtin_bit_cast(unsigned short, ha);
    unsigned short ub = __builtin_bit_cast(unsigned short, hb);
    return (unsigned)ua | ((unsigned)ub << 16);
}

// ---------------------------------------------------------------------------
// prep_c32 (R12): 1024 blocks x 256 thr, ONE record per thread (16 waves/CU).
__global__ __launch_bounds__(256) void prep_c32(const float* __restrict__ pw,
                                                const float* __restrict__ bw,
                                                const float* __restrict__ sw,
                                                const float* __restrict__ sc,
                                                half_t* __restrict__ Ct) {
    int bid = blockIdx.x;
    int i = bid >> 1;
    int j = ((bid & 1) << 8) + threadIdx.x;
    size_t ij = (size_t)i * J_DIM + j;
    float s = sw[ij], b = bw[ij], p = pw[ij];
    const float4* sp4 = (const float4*)(sc + ij * 20);
    unsigned u[16];
#pragma unroll
    for (int v = 0; v < 5; ++v) {
        float4 c4 = sp4[v];
        u[v * 2 + 0] = packh2(s * c4.x, s * c4.y);
        u[v * 2 + 1] = packh2(s * c4.z, s * c4.w);
    }
    u[10] = packh2(b * p, b);
#pragma unroll
    for (int v = 11; v < 16; ++v) u[v] = 0u;
    uint4* dst = (uint4*)(Ct + (size_t)i * KT32 + (size_t)j * SLOT32);
#pragma unroll
    for (int v = 0; v < 4; ++v)
        dst[v] = make_uint4(u[4 * v], u[4 * v + 1], u[4 * v + 2], u[4 * v + 3]);
}

// ---------------------------------------------------------------------------
// kan_fused: R11 structure (grid (8,2,16), 512 thr, 8 waves 2m x 4n, wave-tile
// 128x64, acc[8][4], simple per-phase drain). CHANGE (B): GEN_AS builds the
// 32-slot record in registers (selects vs runtime k0, all static indexing)
// and writes 4 clean swizzled ds_write_b128 — no scattered u16 writes.
__global__ __launch_bounds__(512, 2) void kan_fused(const float* __restrict__ x,
                                                    const half_t* __restrict__ Ct,
                                                    float* __restrict__ out) {
    __shared__ float  xt[32 * 256];        // x-tile, TRANSPOSED [col][b], 32 KB
    __shared__ half_t As[2][BM * 64];      // 2 x 32 KB
    __shared__ half_t Bs[2][BN * 64];      // 2 x 32 KB   -> 160 KiB total

    int lid = blockIdx.x + 8 * (blockIdx.y + 2 * blockIdx.z);   // 0..255
    int c8 = lid & 7;                // XCD
    int r2 = lid >> 3;
    int bz = c8 + 8 * (r2 & 1);      // z in {c8, c8+8}
    int rr2 = r2 >> 1;
    int bx = rr2 & 7;                // 8 m-blocks
    int by = rr2 >> 3;               // 2 n-blocks

    int m0 = bx * BM;
    int n0 = by * BN;
    int j0 = bz * 32;                // this block's 32-j slice

    int t = threadIdx.x;
    int w = t >> 6, l = t & 63;
    int wm = w >> 2, wn = w & 3;     // wave grid 2 x 4
    int q = l >> 4, fr = l & 15;

    const half_t* gB = Ct + (size_t)n0 * KT32 + (size_t)j0 * SLOT32;

    // Bs staging decomposition: per load, wave covers 8 rows x 8 quads (1 KB).
    int srow8 = l >> 3;                      // 0..7 row within 8-row group
    int lq    = (l & 7) ^ (srow8 & 7);       // logical quad at this lane's dest

    floatx4 acc[8][4] = {};

// 4 loads/thread/phase; dest linear (DMA), source pre-swizzled.
#define ISSUE_BS(p, buf)                                                      \
    {                                                                         \
        _Pragma("unroll")                                                     \
        for (int s = 0; s < 4; ++s) {                                         \
            int rB = w * 32 + s * 8 + srow8;                                  \
            __builtin_amdgcn_global_load_lds(                                 \
                (const __attribute__((address_space(1))) unsigned int*)       \
                    (gB + (size_t)rB * KT32 + (p) * 64 + lq * 8),             \
                (__attribute__((address_space(3))) unsigned int*)             \
                    (&Bs[buf][(w * 32 + s * 8) * 64]),                        \
                16, 0, 0);                                                    \
        }                                                                     \
    }

// One A-record per thread, REGISTER-BUILT: uint s2 covers slots {2s2, 2s2+1}.
// Window [k0, k0+4] (k>=0) holds Nv; slots 20,21 = neg,pos; rest 0.
// Values byte-identical to the R11 scatter version. 4 swizzled b128 writes,
// conflict-free by the (quad ^ (row&7)) involution.
#define GEN_AS(p, buf)                                                        \
    {                                                                         \
        int bl = t & 255, jp = t >> 8;                                        \
        int rx = bl & 7;                                                      \
        float xv = xt[((p) * 2 + jp) * 256 + bl];                             \
        float xc = fminf(fmaxf(xv, -1.f), 1.f);                               \
        float pos = fmaxf(xc, 0.f);                                           \
        float neg = xc - pos;                                                 \
        int k0; float Nv[5];                                                  \
        bspline5(xc, k0, Nv);                                                 \
        half_t* rb = &As[buf][bl * 64];                                       \
        _Pragma("unroll")                                                     \
        for (int qd = 0; qd < 4; ++qd) {                                      \
            unsigned qq[4];                                                   \
            _Pragma("unroll")                                                 \
            for (int e = 0; e < 4; ++e) {                                     \
                int s2 = qd * 4 + e;                                          \
                if (s2 < 10) {                                                \
                    float lo = 0.f, hi = 0.f;                                 \
                    _Pragma("unroll")                                         \
                    for (int r = 0; r < 5; ++r) {                             \
                        lo = (2 * s2     == k0 + r) ? Nv[r] : lo;             \
                        hi = (2 * s2 + 1 == k0 + r) ? Nv[r] : hi;             \
                    }                                                         \
                    qq[e] = packh2(lo, hi);                                   \
                } else if (s2 == 10) {                                        \
                    qq[e] = packh2(neg, pos);                                 \
                } else {                                                      \
                    qq[e] = 0u;                                               \
                }                                                             \
            }                                                                 \
            *(uint4*)(rb + ((jp * 4 + qd) ^ rx) * 8) =                        \
                make_uint4(qq[0], qq[1], qq[2], qq[3]);                       \
        }                                                                     \
    }

    // ---- prologue: Bs[0] in flight; x-tile transposed into LDS; As[0] built.
    ISSUE_BS(0, 0)
#pragma unroll
    for (int v = 0; v < 4; ++v) {
        int r = v * 64 + (t >> 3);           // 0..255
        int cq = t & 7;                      // col-quad 0..7
        float4 xv4 = *(const float4*)(x + (size_t)(m0 + r) * J_DIM + j0 + cq * 4);
#pragma unroll
        for (int c = 0; c < 4; ++c)
            xt[(cq * 4 + c) * 256 + r] = ((const float*)&xv4)[c];
    }
    __syncthreads();                         // xt visible (also drains Bs[0])
    GEN_AS(0, 0)

    // ---- main loop: 16 phases of 2 j (K=64) each.
    for (int p = 0; p < NPH; ++p) {
        asm volatile("s_waitcnt vmcnt(0) lgkmcnt(0)" ::: "memory");
        __builtin_amdgcn_s_barrier();        // Bs[p] + As[p] ready; buf (p+1)&1 free

        if (p + 1 < NPH) ISSUE_BS(p + 1, (p + 1) & 1)

        const half_t* Ab = &As[p & 1][0];
        const half_t* Bb = &Bs[p & 1][0];
#pragma unroll
        for (int ks = 0; ks < 2; ++ks) {
            half8 af[8], bf[4];
#pragma unroll
            for (int nt = 0; nt < 4; ++nt)
                bf[nt] = *(const half8*)(Bb + (wn * 64 + nt * 16 + fr) * 64
                                            + (((ks * 4 + q) ^ (fr & 7)) * 8));
#pragma unroll
            for (int mt = 0; mt < 8; ++mt)
                af[mt] = *(const half8*)(Ab + (wm * 128 + mt * 16 + fr) * 64
                                            + (((ks * 4 + q) ^ (fr & 7)) * 8));
            __builtin_amdgcn_s_setprio(1);
#pragma unroll
            for (int mt = 0; mt < 8; ++mt)
#pragma unroll
                for (int nt = 0; nt < 4; ++nt)
                    acc[mt][nt] = __builtin_amdgcn_mfma_f32_16x16x32_f16(
                        af[mt], bf[nt], acc[mt][nt], 0, 0, 0);
            __builtin_amdgcn_s_setprio(0);
        }
        if (p + 1 < NPH) GEN_AS(p + 1, (p + 1) & 1)
    }
#undef GEN_AS
#undef ISSUE_BS

    // epilogue (verified): C/D col = lane&15, row = (lane>>4)*4 + reg.
    // (A): padded slice stride breaks the 4 MB power-of-2 channel alias.
    float* dst = out + (size_t)bz * SLICE_F;
#pragma unroll
    for (int mt = 0; mt < 8; ++mt)
#pragma unroll
        for (int nt = 0; nt < 4; ++nt) {
            int rw = m0 + wm * 128 + mt * 16 + q * 4;
            int cc = n0 + wn * 64 + nt * 16 + fr;
#pragma unroll
            for (int rg = 0; rg < 4; ++rg)
                dst[(size_t)(rw + rg) * O_DIM + cc] = acc[mt][nt][rg];
        }
}

// ---------------------------------------------------------------------------
// Sum the KSPLIT padded partial slices into out. 71 MB traffic, BW-bound.
__global__ __launch_bounds__(256) void reduce16(const float* __restrict__ parts,
                                                float* __restrict__ out) {
    constexpr int S4 = SLICE_F / 4;               // padded slice stride (float4)
    int i = blockIdx.x * 256 + threadIdx.x;       // float4 index
    const float4* p = (const float4*)parts;
    float4 a = p[i];
#pragma unroll
    for (int z = 1; z < KSPLIT; ++z) {
        float4 b = p[(size_t)z * S4 + i];
        a.x += b.x; a.y += b.y; a.z += b.z; a.w += b.w;
    }
    ((float4*)out)[i] = a;
}

// ---------------------------------------------------------------------------
// Zero-workspace fallback (only if ws_size too small): correct but slow.
__global__ __launch_bounds__(256) void kan_fallback(const float* __restrict__ x,
                                                    const float* __restrict__ pw,
                                                    const float* __restrict__ bw,
                                                    const float* __restrict__ sw,
                                                    const float* __restrict__ sc,
                                                    float* __restrict__ out) {
    __shared__ float s_neg[J_DIM], s_pos[J_DIM], s_bas[J_DIM][5];
    __shared__ int s_k0[J_DIM];
    int b = blockIdx.x;
    int t = threadIdx.x;
#pragma unroll
    for (int jj = 0; jj < 2; ++jj) {
        int j = t + jj * 256;
        float xv = x[(size_t)b * J_DIM + j];
        float xc = fminf(fmaxf(xv, -1.f), 1.f);
        float pos = fmaxf(xc, 0.f);
        s_pos[j] = pos;
        s_neg[j] = xc - pos;
        int k0; float Nv[5];
        bspline5(xc, k0, Nv);
        s_k0[j] = k0;
#pragma unroll
        for (int r = 0; r < 5; ++r) s_bas[j][r] = Nv[r];
    }
    __syncthreads();
    for (int i = t; i < O_DIM; i += 256) {
        float acc = 0.f;
        for (int j = 0; j < J_DIM; ++j) {
            size_t ij = (size_t)i * J_DIM + j;
            float bwv = bw[ij];
            acc += bwv * (pw[ij] * s_neg[j] + s_pos[j]);
            int k0 = s_k0[j];
            const float* cp = sc + ij * 20;
            float sp = 0.f;
#pragma unroll
            for (int r = 0; r < 5; ++r) {
                int k = k0 + r;
                if (k >= 0) sp += s_bas[j][r] * cp[k];
            }
            acc += sw[ij] * sp;
        }
        out[(size_t)b * O_DIM + i] = acc;
    }
}

// ---------------------------------------------------------------------------
extern "C" void kernel_launch(void* const* d_in, const int* in_sizes, int n_in,
                              void* d_out, int out_size, void* d_ws, size_t ws_size,
                              hipStream_t stream) {
    const float* x  = (const float*)d_in[0];
    const float* pw = (const float*)d_in[1];
    const float* bw = (const float*)d_in[2];
    const float* sw = (const float*)d_in[3];
    const float* sc = (const float*)d_in[4];
    float* out = (float*)d_out;

    const size_t ct32_bytes  = (size_t)O_DIM * KT32 * sizeof(half_t);           // 16.8 MB
    const size_t parts_bytes = (size_t)KSPLIT * SLICE_F * sizeof(float);        // 67.2 MB

    if (ws_size >= ct32_bytes + parts_bytes) {
        half_t* Ct32 = (half_t*)d_ws;
        float* parts = (float*)((char*)d_ws + ct32_bytes);   // 16B-aligned

        prep_c32<<<O_DIM * 2, 256, 0, stream>>>(pw, bw, sw, sc, Ct32);
        dim3 g(B_DIM / BM, O_DIM / BN, KSPLIT);              // (8, 2, 16)
        kan_fused<<<g, 512, 0, stream>>>(x, Ct32, parts);
        reduce16<<<(B_DIM * O_DIM / 4) / 256, 256, 0, stream>>>(parts, out);
    } else {
        kan_fallback<<<B_DIM, 256, 0, stream>>>(x, pw, bw, sw, sc, out);
    }
}